// Round 8
// baseline (334.122 us; speedup 1.0000x reference)
//
#include <hip/hip_runtime.h>
#include <hip/hip_fp16.h>

// GIN forward, round 8:
//  - layer 0 gathers in input width 64 (s = x+agg, 77MB not 154MB), GEMM0 gets
//    fused bias+relu epilogue
//  - gather: ONE wave per node, EP edges/iter (EP=64/(F/8)), per-group strided
//    edges + __shfl_xor cross-group reduce -> no cross-node degree serialization
//  - prep_k zeroes cnt; scan_write_k inlines the 49-partial scan + zeroes fill
//    (drops scan_small_k and both memsets): 14 dispatches total

#define N_NODES  50000
#define N_EDGES  600000
#define N_FEAT   64
#define DIM      128
#define N_GRAPHS 1024
#define NB_SCAN  49   // ceil(50000/1024)

typedef _Float16 f16x8 __attribute__((ext_vector_type(8)));
typedef float    f32x4 __attribute__((ext_vector_type(4)));

// ---------------- CSR build ----------------
__global__ __launch_bounds__(256) void hist_k(
    const int* __restrict__ dst, int* __restrict__ cnt) {
  int e = blockIdx.x * 256 + threadIdx.x;
  if (e < N_EDGES) atomicAdd(&cnt[dst[e]], 1);
}

__global__ __launch_bounds__(256) void scan_part_k(
    const int* __restrict__ cnt, int* __restrict__ part) {
  __shared__ int ws[4];
  int t = threadIdx.x, b = blockIdx.x;
  int base = b * 1024 + t * 4;
  int s = 0;
  if (base + 3 < N_NODES) {
    int4 v = *reinterpret_cast<const int4*>(cnt + base);
    s = v.x + v.y + v.z + v.w;
  } else {
    for (int i = 0; i < 4; ++i) if (base + i < N_NODES) s += cnt[base + i];
  }
  for (int off = 32; off; off >>= 1) s += __shfl_down(s, off, 64);
  int lane = t & 63, wv = t >> 6;
  if (lane == 0) ws[wv] = s;
  __syncthreads();
  if (t == 0) part[b] = ws[0] + ws[1] + ws[2] + ws[3];
}

// intra-block scan + inlined partial-scan (wave 0) + fill zeroing -> row_ptr
__global__ __launch_bounds__(256) void scan_write_k(
    const int* __restrict__ cnt, const int* __restrict__ part,
    int* __restrict__ row_ptr, int* __restrict__ fill) {
  __shared__ int wsum[4];
  __shared__ int blk_off_s;
  int t = threadIdx.x, b = blockIdx.x;
  int lane = t & 63, wv = t >> 6;
  int base = b * 1024 + t * 4;

  // zero fill (covered by same index range)
  if (base + 3 < N_NODES)
    *reinterpret_cast<int4*>(fill + base) = make_int4(0, 0, 0, 0);
  else
    for (int i = 0; i < 4; ++i) if (base + i < N_NODES) fill[base + i] = 0;

  // wave 0: exclusive-scan the 49 partials, keep this block's offset
  if (t < 64) {
    int v = (t < NB_SCAN) ? part[t] : 0;
    int incl = v;
    for (int off = 1; off < 64; off <<= 1) {
      int u = __shfl_up(incl, off, 64);
      if (t >= off) incl += u;
    }
    if (t == b) blk_off_s = incl - v;
  }

  int v[4];
#pragma unroll
  for (int i = 0; i < 4; ++i) v[i] = (base + i < N_NODES) ? cnt[base + i] : 0;
  int ls = v[0] + v[1] + v[2] + v[3];
  int incl = ls;
  for (int off = 1; off < 64; off <<= 1) {
    int u = __shfl_up(incl, off, 64);
    if (lane >= off) incl += u;
  }
  if (lane == 63) wsum[wv] = incl;
  __syncthreads();
  int woff = 0;
  for (int w = 0; w < wv; ++w) woff += wsum[w];
  int off0 = blk_off_s + woff + (incl - ls);
  int rp0 = off0, rp1 = off0 + v[0], rp2 = rp1 + v[1], rp3 = rp2 + v[2];
  if (base + 3 < N_NODES)
    *reinterpret_cast<int4*>(row_ptr + base) = make_int4(rp0, rp1, rp2, rp3);
  else {
    int rp[4] = {rp0, rp1, rp2, rp3};
    for (int i = 0; i < 4; ++i) if (base + i < N_NODES) row_ptr[base + i] = rp[i];
  }
  if (b == 0 && t == 0) row_ptr[N_NODES] = N_EDGES;
}

__global__ __launch_bounds__(256) void fill_k(
    const int* __restrict__ src, const int* __restrict__ dst,
    const int* __restrict__ row_ptr, int* __restrict__ fill,
    int* __restrict__ csr_src) {
  int e = blockIdx.x * 256 + threadIdx.x;
  if (e >= N_EDGES) return;
  int d = dst[e];
  int pos = row_ptr[d] + atomicAdd(&fill[d], 1);
  csr_src[pos] = src[e];
}

// ---- merged prep: zero cnt ; x->fp16 ; W[K][128] -> Wt[128][K] fp16 ----
#define CNTZ  (N_NODES / 4)            // 12500 int4 items
#define XWORK (N_NODES * N_FEAT / 4)   // 800000 float4 items
__global__ __launch_bounds__(256) void prep_k(
    const float* __restrict__ x, __half* __restrict__ xh,
    const float* __restrict__ w0, const float* __restrict__ w1,
    const float* __restrict__ w2, const float* __restrict__ w3,
    __half* __restrict__ Wt0, __half* __restrict__ Wt1,
    __half* __restrict__ Wt2, __half* __restrict__ Wt3,
    int* __restrict__ cnt) {
  int i = blockIdx.x * 256 + threadIdx.x;
  if (i < CNTZ) {
    *reinterpret_cast<int4*>(cnt + i * 4) = make_int4(0, 0, 0, 0);
    return;
  }
  i -= CNTZ;
  if (i < XWORK) {
    float4 v = *reinterpret_cast<const float4*>(x + (size_t)i * 4);
    union { __half2 h2[2]; uint2 u; } pk;
    pk.h2[0] = __floats2half2_rn(v.x, v.y);
    pk.h2[1] = __floats2half2_rn(v.z, v.w);
    *reinterpret_cast<uint2*>(xh + (size_t)i * 4) = pk.u;
    return;
  }
  int j = i - XWORK;
  if (j < N_FEAT * DIM) {               // w0: [64][128] -> Wt0[128][64]
    int k = j >> 7, n = j & 127;
    Wt0[n * N_FEAT + k] = __float2half(w0[j]);
    return;
  }
  j -= N_FEAT * DIM;
  if (j >= 3 * DIM * DIM) return;
  int wsel = j / (DIM * DIM);
  int jj = j - wsel * (DIM * DIM);
  int k = jj >> 7, n = jj & 127;
  const float* W = (wsel == 0) ? w1 : (wsel == 1) ? w2 : w3;
  __half* Wt     = (wsel == 0) ? Wt1 : (wsel == 1) ? Wt2 : Wt3;
  Wt[n * DIM + k] = __float2half(W[jj]);
}

// ------------- MFMA GEMM: y[M][128] = A[M][K] @ Wt[128][K]^T -------------
// EPI: epilogue relu(v + bias[col]) (used for layer 0 where gather precedes).
template<int K, bool EPI>
__global__ __launch_bounds__(256) void mfma_gemm_k(
    const __half* __restrict__ A, const __half* __restrict__ Wt,
    const float* __restrict__ bias, __half* __restrict__ y, int M) {
  constexpr int KP = K + 8;
  __shared__ __align__(16) __half As[64][KP];
  __shared__ __align__(16) __half Ws[128][KP];

  int tid = threadIdx.x;
  int row0 = blockIdx.x * 64;

  for (int i = tid; i < 64 * (K / 8); i += 256) {
    int r = i / (K / 8), c = (i % (K / 8)) * 8;
    int row = row0 + r;
    f16x8 v = {};
    if (row < M) v = *reinterpret_cast<const f16x8*>(A + (size_t)row * K + c);
    *reinterpret_cast<f16x8*>(&As[r][c]) = v;
  }
  for (int i = tid; i < 128 * (K / 8); i += 256) {
    int r = i / (K / 8), c = (i % (K / 8)) * 8;
    *reinterpret_cast<f16x8*>(&Ws[r][c]) =
        *reinterpret_cast<const f16x8*>(Wt + (size_t)r * K + c);
  }
  __syncthreads();

  int w = tid >> 6, lane = tid & 63;
  int quad = lane >> 4, m = lane & 15;

  f32x4 acc[8];
#pragma unroll
  for (int t = 0; t < 8; ++t) acc[t] = (f32x4){0.f, 0.f, 0.f, 0.f};

#pragma unroll
  for (int kk = 0; kk < K; kk += 32) {
    f16x8 a = *reinterpret_cast<const f16x8*>(&As[w * 16 + m][kk + quad * 8]);
#pragma unroll
    for (int t = 0; t < 8; ++t) {
      f16x8 b = *reinterpret_cast<const f16x8*>(&Ws[t * 16 + m][kk + quad * 8]);
      acc[t] = __builtin_amdgcn_mfma_f32_16x16x32_f16(a, b, acc[t], 0, 0, 0);
    }
  }

#pragma unroll
  for (int t = 0; t < 8; ++t) {
    float bv = EPI ? bias[t * 16 + m] : 0.f;
#pragma unroll
    for (int r = 0; r < 4; ++r) {
      int row = row0 + w * 16 + quad * 4 + r;
      if (row < M) {
        float v = acc[t][r];
        if (EPI) v = fmaxf(v + bv, 0.f);
        y[(size_t)row * 128 + t * 16 + m] = __float2half(v);
      }
    }
  }
}

// ---- gather: ONE wave per node. CH = F/8 16B-chunks per row; EP = 64/CH
// edges processed per iteration (per-group strided), __shfl_xor reduce.
// BR: out = relu(self + sum + bias); else out = self + sum (no bias/relu).
template<int F, bool BR>
__global__ __launch_bounds__(256) void gather_k(
    const __half* __restrict__ y, const int* __restrict__ row_ptr,
    const int* __restrict__ csr_src, const float* __restrict__ bias,
    __half* __restrict__ hout) {
  constexpr int CH = F / 8;
  constexpr int EP = 64 / CH;
  const f16x8* yv = reinterpret_cast<const f16x8*>(y);
  int node = (blockIdx.x * 256 + threadIdx.x) >> 6;
  if (node >= N_NODES) return;
  int lane = threadIdx.x & 63;
  int grp = lane / CH;
  int l   = lane % CH;
  int beg = row_ptr[node], end = row_ptr[node + 1];

  float acc[8];
#pragma unroll
  for (int v = 0; v < 8; ++v) acc[v] = 0.f;

  int e = beg + grp;
  for (; e + EP < end; e += 2 * EP) {      // 2x unroll
    int s0 = csr_src[e];
    int s1 = csr_src[e + EP];
    f16x8 v0 = yv[(size_t)s0 * CH + l];
    f16x8 v1 = yv[(size_t)s1 * CH + l];
#pragma unroll
    for (int v = 0; v < 8; ++v) acc[v] += (float)v0[v] + (float)v1[v];
  }
  if (e < end) {
    f16x8 v0 = yv[(size_t)csr_src[e] * CH + l];
#pragma unroll
    for (int v = 0; v < 8; ++v) acc[v] += (float)v0[v];
  }

  // cross-group reduce (groups aligned: xor offsets CH..32 preserve l)
#pragma unroll
  for (int off = CH; off < 64; off <<= 1)
#pragma unroll
    for (int v = 0; v < 8; ++v) acc[v] += __shfl_xor(acc[v], off, 64);

  if (lane < CH) {
    f16x8 self = yv[(size_t)node * CH + lane];
    f16x8 o;
    if (BR) {
      float4 b0 = *reinterpret_cast<const float4*>(bias + lane * 8);
      float4 b1 = *reinterpret_cast<const float4*>(bias + lane * 8 + 4);
      float bb[8] = {b0.x, b0.y, b0.z, b0.w, b1.x, b1.y, b1.z, b1.w};
#pragma unroll
      for (int v = 0; v < 8; ++v)
        o[v] = (_Float16)fmaxf(acc[v] + (float)self[v] + bb[v], 0.f);
    } else {
#pragma unroll
      for (int v = 0; v < 8; ++v)
        o[v] = (_Float16)(acc[v] + (float)self[v]);
    }
    reinterpret_cast<f16x8*>(hout)[(size_t)node * CH + lane] = o;
  }
}

// ---- fused mean-pool (sorted batch) + post-MLP (fp32) ----
__global__ __launch_bounds__(128) void pool_post_k(
    const __half* __restrict__ h, const int* __restrict__ batch,
    const float* __restrict__ W, const float* __restrict__ bias,
    float* __restrict__ out) {
  __shared__ float xs[DIM];
  int g = blockIdx.x;
  int col = threadIdx.x;
  int lo = 0, hi = N_NODES;
  while (lo < hi) { int mid = (lo + hi) >> 1; if (batch[mid] < g) lo = mid + 1; else hi = mid; }
  int beg = lo;
  hi = N_NODES;
  while (lo < hi) { int mid = (lo + hi) >> 1; if (batch[mid] < g + 1) lo = mid + 1; else hi = mid; }
  int end = lo;

  float acc = 0.f;
  for (int n = beg; n < end; ++n) acc += __half2float(h[(size_t)n * DIM + col]);
  float cnt = fmaxf((float)(end - beg), 1.0f);
  xs[col] = acc / cnt;
  __syncthreads();
  float o = bias[col];
  for (int k = 0; k < DIM; ++k)
    o = fmaf(xs[k], W[(size_t)k * DIM + col], o);
  out[(size_t)g * DIM + col] = fmaxf(o, 0.f);
}

extern "C" void kernel_launch(void* const* d_in, const int* in_sizes, int n_in,
                              void* d_out, int out_size, void* d_ws, size_t ws_size,
                              hipStream_t stream) {
  const float* x    = (const float*)d_in[0];
  const int*   ei   = (const int*)d_in[1];
  const int*   batch= (const int*)d_in[2];
  const float* w0 = (const float*)d_in[3];  const float* b0 = (const float*)d_in[4];
  const float* w1 = (const float*)d_in[5];  const float* b1 = (const float*)d_in[6];
  const float* w2 = (const float*)d_in[7];  const float* b2 = (const float*)d_in[8];
  const float* w3 = (const float*)d_in[9];  const float* b3 = (const float*)d_in[10];
  const float* wp = (const float*)d_in[11]; const float* bp = (const float*)d_in[12];
  float* out = (float*)d_out;

  const int* src = ei;
  const int* dst = ei + N_EDGES;

  // ws layout: xh[50000*64]h | y[50000*128]h (s uses first half) | h[50000*128]h
  //          | Wt0 | Wt1..3 | cnt | fill | part[64] | row_ptr | csr_src
  __half* xh = (__half*)d_ws;
  __half* y  = xh + (size_t)N_NODES * N_FEAT;
  __half* h  = y  + (size_t)N_NODES * DIM;
  __half* Wt0 = h + (size_t)N_NODES * DIM;
  __half* Wt1 = Wt0 + N_FEAT * DIM;
  __half* Wt2 = Wt1 + DIM * DIM;
  __half* Wt3 = Wt2 + DIM * DIM;
  int* cnt     = (int*)(Wt3 + DIM * DIM);
  int* fill    = cnt + N_NODES;
  int* part    = fill + N_NODES;
  int* row_ptr = part + 64;
  int* csr_src = row_ptr + (N_NODES + 1);
  __half* s = y;   // 64-wide staging for layer 0 (y unused until GEMM1)

  // ---- prep (zeros cnt) then CSR build ----
  {
    int total = CNTZ + XWORK + N_FEAT * DIM + 3 * DIM * DIM;
    prep_k<<<(total + 255) / 256, 256, 0, stream>>>(x, xh, w0, w1, w2, w3,
                                                    Wt0, Wt1, Wt2, Wt3, cnt);
  }
  hist_k<<<(N_EDGES + 255) / 256, 256, 0, stream>>>(dst, cnt);
  scan_part_k <<<NB_SCAN, 256, 0, stream>>>(cnt, part);
  scan_write_k<<<NB_SCAN, 256, 0, stream>>>(cnt, part, row_ptr, fill);
  fill_k<<<(N_EDGES + 255) / 256, 256, 0, stream>>>(src, dst, row_ptr, fill, csr_src);

  int ggrid = (N_NODES * 64 + 255) / 256;   // one wave per node
  int mgrid = (N_NODES + 63) / 64;

  // ---- layer 0: s = x + agg(x) (64-wide), h = relu(s@W0 + b0) ----
  gather_k<N_FEAT, false><<<ggrid, 256, 0, stream>>>(xh, row_ptr, csr_src, nullptr, s);
  mfma_gemm_k<N_FEAT, true><<<mgrid, 256, 0, stream>>>(s, Wt0, b0, h, N_NODES);

  // ---- layers 1..3: y = h@W, h = relu(y_i + sum y_j + b) ----
  const __half* Wl[3] = {Wt1, Wt2, Wt3};
  const float*  Bl[3] = {b1, b2, b3};
  for (int l = 0; l < 3; ++l) {
    mfma_gemm_k<DIM, false><<<mgrid, 256, 0, stream>>>(h, Wl[l], nullptr, y, N_NODES);
    gather_k<DIM, true><<<ggrid, 256, 0, stream>>>(y, row_ptr, csr_src, Bl[l], h);
  }

  // ---- pool + post-MLP ----
  pool_post_k<<<N_GRAPHS, 128, 0, stream>>>(h, batch, wp, bp, out);
}

// Round 9
// 311.707 us; speedup vs baseline: 1.0719x; 1.0719x over previous
//
#include <hip/hip_runtime.h>
#include <hip/hip_fp16.h>

// GIN forward, round 9:
//  - gather reverted to R7 shape (F/8 lanes/node, f16x8, 4-deep unroll),
//    templated width: layer 0 gathers at width 64 (77MB not 154MB)
//  - MFMA GEMM epilogue: LDS repack (aliases staging LDS, +16-half pad) ->
//    coalesced f16x8 stores (was 32 scalar 2B stores/lane)
//  - keeps R8 launch structure: 13 dispatches

#define N_NODES  50000
#define N_EDGES  600000
#define N_FEAT   64
#define DIM      128
#define N_GRAPHS 1024
#define NB_SCAN  49   // ceil(50000/1024)

typedef _Float16 f16x8 __attribute__((ext_vector_type(8)));
typedef float    f32x4 __attribute__((ext_vector_type(4)));

// ---------------- CSR build ----------------
__global__ __launch_bounds__(256) void hist_k(
    const int* __restrict__ dst, int* __restrict__ cnt) {
  int e = blockIdx.x * 256 + threadIdx.x;
  if (e < N_EDGES) atomicAdd(&cnt[dst[e]], 1);
}

__global__ __launch_bounds__(256) void scan_part_k(
    const int* __restrict__ cnt, int* __restrict__ part) {
  __shared__ int ws[4];
  int t = threadIdx.x, b = blockIdx.x;
  int base = b * 1024 + t * 4;
  int s = 0;
  if (base + 3 < N_NODES) {
    int4 v = *reinterpret_cast<const int4*>(cnt + base);
    s = v.x + v.y + v.z + v.w;
  } else {
    for (int i = 0; i < 4; ++i) if (base + i < N_NODES) s += cnt[base + i];
  }
  for (int off = 32; off; off >>= 1) s += __shfl_down(s, off, 64);
  int lane = t & 63, wv = t >> 6;
  if (lane == 0) ws[wv] = s;
  __syncthreads();
  if (t == 0) part[b] = ws[0] + ws[1] + ws[2] + ws[3];
}

// intra-block scan + inlined partial-scan (wave 0) + fill zeroing -> row_ptr
__global__ __launch_bounds__(256) void scan_write_k(
    const int* __restrict__ cnt, const int* __restrict__ part,
    int* __restrict__ row_ptr, int* __restrict__ fill) {
  __shared__ int wsum[4];
  __shared__ int blk_off_s;
  int t = threadIdx.x, b = blockIdx.x;
  int lane = t & 63, wv = t >> 6;
  int base = b * 1024 + t * 4;

  if (base + 3 < N_NODES)
    *reinterpret_cast<int4*>(fill + base) = make_int4(0, 0, 0, 0);
  else
    for (int i = 0; i < 4; ++i) if (base + i < N_NODES) fill[base + i] = 0;

  if (t < 64) {
    int v = (t < NB_SCAN) ? part[t] : 0;
    int incl = v;
    for (int off = 1; off < 64; off <<= 1) {
      int u = __shfl_up(incl, off, 64);
      if (t >= off) incl += u;
    }
    if (t == b) blk_off_s = incl - v;
  }

  int v[4];
#pragma unroll
  for (int i = 0; i < 4; ++i) v[i] = (base + i < N_NODES) ? cnt[base + i] : 0;
  int ls = v[0] + v[1] + v[2] + v[3];
  int incl = ls;
  for (int off = 1; off < 64; off <<= 1) {
    int u = __shfl_up(incl, off, 64);
    if (lane >= off) incl += u;
  }
  if (lane == 63) wsum[wv] = incl;
  __syncthreads();
  int woff = 0;
  for (int w = 0; w < wv; ++w) woff += wsum[w];
  int off0 = blk_off_s + woff + (incl - ls);
  int rp0 = off0, rp1 = off0 + v[0], rp2 = rp1 + v[1], rp3 = rp2 + v[2];
  if (base + 3 < N_NODES)
    *reinterpret_cast<int4*>(row_ptr + base) = make_int4(rp0, rp1, rp2, rp3);
  else {
    int rp[4] = {rp0, rp1, rp2, rp3};
    for (int i = 0; i < 4; ++i) if (base + i < N_NODES) row_ptr[base + i] = rp[i];
  }
  if (b == 0 && t == 0) row_ptr[N_NODES] = N_EDGES;
}

__global__ __launch_bounds__(256) void fill_k(
    const int* __restrict__ src, const int* __restrict__ dst,
    const int* __restrict__ row_ptr, int* __restrict__ fill,
    int* __restrict__ csr_src) {
  int e = blockIdx.x * 256 + threadIdx.x;
  if (e >= N_EDGES) return;
  int d = dst[e];
  int pos = row_ptr[d] + atomicAdd(&fill[d], 1);
  csr_src[pos] = src[e];
}

// ---- merged prep: zero cnt ; x->fp16 ; W[K][128] -> Wt[128][K] fp16 ----
#define CNTZ  (N_NODES / 4)
#define XWORK (N_NODES * N_FEAT / 4)
__global__ __launch_bounds__(256) void prep_k(
    const float* __restrict__ x, __half* __restrict__ xh,
    const float* __restrict__ w0, const float* __restrict__ w1,
    const float* __restrict__ w2, const float* __restrict__ w3,
    __half* __restrict__ Wt0, __half* __restrict__ Wt1,
    __half* __restrict__ Wt2, __half* __restrict__ Wt3,
    int* __restrict__ cnt) {
  int i = blockIdx.x * 256 + threadIdx.x;
  if (i < CNTZ) {
    *reinterpret_cast<int4*>(cnt + i * 4) = make_int4(0, 0, 0, 0);
    return;
  }
  i -= CNTZ;
  if (i < XWORK) {
    float4 v = *reinterpret_cast<const float4*>(x + (size_t)i * 4);
    union { __half2 h2[2]; uint2 u; } pk;
    pk.h2[0] = __floats2half2_rn(v.x, v.y);
    pk.h2[1] = __floats2half2_rn(v.z, v.w);
    *reinterpret_cast<uint2*>(xh + (size_t)i * 4) = pk.u;
    return;
  }
  int j = i - XWORK;
  if (j < N_FEAT * DIM) {
    int k = j >> 7, n = j & 127;
    Wt0[n * N_FEAT + k] = __float2half(w0[j]);
    return;
  }
  j -= N_FEAT * DIM;
  if (j >= 3 * DIM * DIM) return;
  int wsel = j / (DIM * DIM);
  int jj = j - wsel * (DIM * DIM);
  int k = jj >> 7, n = jj & 127;
  const float* W = (wsel == 0) ? w1 : (wsel == 1) ? w2 : w3;
  __half* Wt     = (wsel == 0) ? Wt1 : (wsel == 1) ? Wt2 : Wt3;
  Wt[n * DIM + k] = __float2half(W[jj]);
}

// ------------- MFMA GEMM: y[M][128] = A[M][K] @ Wt[128][K]^T -------------
// Epilogue repacks through LDS (aliases staging) for coalesced f16x8 stores.
template<int K, bool EPI>
__global__ __launch_bounds__(256) void mfma_gemm_k(
    const __half* __restrict__ A, const __half* __restrict__ Wt,
    const float* __restrict__ bias, __half* __restrict__ y, int M) {
  constexpr int KP = K + 8;
  constexpr int OSP = 128 + 16;   // pad 32B: quad banks at 0/8/16/24
  constexpr size_t STAGE = (size_t)(64 + 128) * KP * sizeof(__half);
  constexpr size_t OUTSZ = (size_t)64 * OSP * sizeof(__half);
  __shared__ __align__(16) char smem[STAGE > OUTSZ ? STAGE : OUTSZ];
  __half (*As)[KP]  = reinterpret_cast<__half(*)[KP]>(smem);
  __half (*Ws)[KP]  = reinterpret_cast<__half(*)[KP]>(smem + (size_t)64 * KP * sizeof(__half));
  __half (*Os)[OSP] = reinterpret_cast<__half(*)[OSP]>(smem);

  int tid = threadIdx.x;
  int row0 = blockIdx.x * 64;

  for (int i = tid; i < 64 * (K / 8); i += 256) {
    int r = i / (K / 8), c = (i % (K / 8)) * 8;
    int row = row0 + r;
    f16x8 v = {};
    if (row < M) v = *reinterpret_cast<const f16x8*>(A + (size_t)row * K + c);
    *reinterpret_cast<f16x8*>(&As[r][c]) = v;
  }
  for (int i = tid; i < 128 * (K / 8); i += 256) {
    int r = i / (K / 8), c = (i % (K / 8)) * 8;
    *reinterpret_cast<f16x8*>(&Ws[r][c]) =
        *reinterpret_cast<const f16x8*>(Wt + (size_t)r * K + c);
  }
  __syncthreads();

  int w = tid >> 6, lane = tid & 63;
  int quad = lane >> 4, m = lane & 15;

  f32x4 acc[8];
#pragma unroll
  for (int t = 0; t < 8; ++t) acc[t] = (f32x4){0.f, 0.f, 0.f, 0.f};

#pragma unroll
  for (int kk = 0; kk < K; kk += 32) {
    f16x8 a = *reinterpret_cast<const f16x8*>(&As[w * 16 + m][kk + quad * 8]);
#pragma unroll
    for (int t = 0; t < 8; ++t) {
      f16x8 b = *reinterpret_cast<const f16x8*>(&Ws[t * 16 + m][kk + quad * 8]);
      acc[t] = __builtin_amdgcn_mfma_f32_16x16x32_f16(a, b, acc[t], 0, 0, 0);
    }
  }

  __syncthreads();   // all LDS reads done; Os aliases As/Ws

#pragma unroll
  for (int t = 0; t < 8; ++t) {
    float bv = EPI ? bias[t * 16 + m] : 0.f;
#pragma unroll
    for (int r = 0; r < 4; ++r) {
      float v = acc[t][r];
      if (EPI) v = fmaxf(v + bv, 0.f);
      Os[w * 16 + quad * 4 + r][t * 16 + m] = __float2half(v);
    }
  }
  __syncthreads();

  // coalesced store: 1024 f16x8 chunks over 256 threads
#pragma unroll
  for (int it = 0; it < 4; ++it) {
    int i = tid + it * 256;
    int r = i >> 4, c = (i & 15) * 8;
    int row = row0 + r;
    if (row < M)
      *reinterpret_cast<f16x8*>(y + (size_t)row * 128 + c) =
          *reinterpret_cast<const f16x8*>(&Os[r][c]);
  }
}

// ---- gather + optional bias/relu. F/8 lanes per node, f16x8 per lane,
// 4-deep independent loads (R7 shape). fp32 accumulate.
template<int F, bool BR>
__global__ __launch_bounds__(256) void gather_k(
    const __half* __restrict__ y, const int* __restrict__ row_ptr,
    const int* __restrict__ csr_src, const float* __restrict__ bias,
    __half* __restrict__ hout) {
  constexpr int CH = F / 8;     // lanes per node
  const f16x8* yv = reinterpret_cast<const f16x8*>(y);
  int gid  = blockIdx.x * 256 + threadIdx.x;
  int node = gid / CH;
  int l    = gid % CH;
  if (node >= N_NODES) return;
  int beg = row_ptr[node], end = row_ptr[node + 1];

  f16x8 self = yv[(size_t)node * CH + l];
  float acc[8];
#pragma unroll
  for (int v = 0; v < 8; ++v) acc[v] = (float)self[v];

  int e = beg;
  for (; e + 3 < end; e += 4) {
    int s0 = csr_src[e+0], s1 = csr_src[e+1], s2 = csr_src[e+2], s3 = csr_src[e+3];
    f16x8 v0 = yv[(size_t)s0 * CH + l];
    f16x8 v1 = yv[(size_t)s1 * CH + l];
    f16x8 v2 = yv[(size_t)s2 * CH + l];
    f16x8 v3 = yv[(size_t)s3 * CH + l];
#pragma unroll
    for (int v = 0; v < 8; ++v)
      acc[v] += ((float)v0[v] + (float)v1[v]) + ((float)v2[v] + (float)v3[v]);
  }
  for (; e < end; ++e) {
    f16x8 v0 = yv[(size_t)csr_src[e] * CH + l];
#pragma unroll
    for (int v = 0; v < 8; ++v) acc[v] += (float)v0[v];
  }

  f16x8 o;
  if (BR) {
    float4 b0 = *reinterpret_cast<const float4*>(bias + l * 8);
    float4 b1 = *reinterpret_cast<const float4*>(bias + l * 8 + 4);
    float bb[8] = {b0.x, b0.y, b0.z, b0.w, b1.x, b1.y, b1.z, b1.w};
#pragma unroll
    for (int v = 0; v < 8; ++v) o[v] = (_Float16)fmaxf(acc[v] + bb[v], 0.f);
  } else {
#pragma unroll
    for (int v = 0; v < 8; ++v) o[v] = (_Float16)acc[v];
  }
  reinterpret_cast<f16x8*>(hout)[(size_t)node * CH + l] = o;
}

// ---- fused mean-pool (sorted batch) + post-MLP (fp32) ----
__global__ __launch_bounds__(128) void pool_post_k(
    const __half* __restrict__ h, const int* __restrict__ batch,
    const float* __restrict__ W, const float* __restrict__ bias,
    float* __restrict__ out) {
  __shared__ float xs[DIM];
  int g = blockIdx.x;
  int col = threadIdx.x;
  int lo = 0, hi = N_NODES;
  while (lo < hi) { int mid = (lo + hi) >> 1; if (batch[mid] < g) lo = mid + 1; else hi = mid; }
  int beg = lo;
  hi = N_NODES;
  while (lo < hi) { int mid = (lo + hi) >> 1; if (batch[mid] < g + 1) lo = mid + 1; else hi = mid; }
  int end = lo;

  float acc = 0.f;
  for (int n = beg; n < end; ++n) acc += __half2float(h[(size_t)n * DIM + col]);
  float cnt = fmaxf((float)(end - beg), 1.0f);
  xs[col] = acc / cnt;
  __syncthreads();
  float o = bias[col];
  for (int k = 0; k < DIM; ++k)
    o = fmaf(xs[k], W[(size_t)k * DIM + col], o);
  out[(size_t)g * DIM + col] = fmaxf(o, 0.f);
}

extern "C" void kernel_launch(void* const* d_in, const int* in_sizes, int n_in,
                              void* d_out, int out_size, void* d_ws, size_t ws_size,
                              hipStream_t stream) {
  const float* x    = (const float*)d_in[0];
  const int*   ei   = (const int*)d_in[1];
  const int*   batch= (const int*)d_in[2];
  const float* w0 = (const float*)d_in[3];  const float* b0 = (const float*)d_in[4];
  const float* w1 = (const float*)d_in[5];  const float* b1 = (const float*)d_in[6];
  const float* w2 = (const float*)d_in[7];  const float* b2 = (const float*)d_in[8];
  const float* w3 = (const float*)d_in[9];  const float* b3 = (const float*)d_in[10];
  const float* wp = (const float*)d_in[11]; const float* bp = (const float*)d_in[12];
  float* out = (float*)d_out;

  const int* src = ei;
  const int* dst = ei + N_EDGES;

  __half* xh = (__half*)d_ws;
  __half* y  = xh + (size_t)N_NODES * N_FEAT;
  __half* h  = y  + (size_t)N_NODES * DIM;
  __half* Wt0 = h + (size_t)N_NODES * DIM;
  __half* Wt1 = Wt0 + N_FEAT * DIM;
  __half* Wt2 = Wt1 + DIM * DIM;
  __half* Wt3 = Wt2 + DIM * DIM;
  int* cnt     = (int*)(Wt3 + DIM * DIM);
  int* fill    = cnt + N_NODES;
  int* part    = fill + N_NODES;
  int* row_ptr = part + 64;
  int* csr_src = row_ptr + (N_NODES + 1);
  __half* s = y;   // 64-wide staging for layer 0

  // ---- prep (zeros cnt) then CSR build ----
  {
    int total = CNTZ + XWORK + N_FEAT * DIM + 3 * DIM * DIM;
    prep_k<<<(total + 255) / 256, 256, 0, stream>>>(x, xh, w0, w1, w2, w3,
                                                    Wt0, Wt1, Wt2, Wt3, cnt);
  }
  hist_k<<<(N_EDGES + 255) / 256, 256, 0, stream>>>(dst, cnt);
  scan_part_k <<<NB_SCAN, 256, 0, stream>>>(cnt, part);
  scan_write_k<<<NB_SCAN, 256, 0, stream>>>(cnt, part, row_ptr, fill);
  fill_k<<<(N_EDGES + 255) / 256, 256, 0, stream>>>(src, dst, row_ptr, fill, csr_src);

  int mgrid = (N_NODES + 63) / 64;

  // ---- layer 0: s = x + agg(x) (64-wide), h = relu(s@W0 + b0) ----
  gather_k<N_FEAT, false><<<(N_NODES * (N_FEAT/8) + 255) / 256, 256, 0, stream>>>(
      xh, row_ptr, csr_src, nullptr, s);
  mfma_gemm_k<N_FEAT, true><<<mgrid, 256, 0, stream>>>(s, Wt0, b0, h, N_NODES);

  // ---- layers 1..3 ----
  const __half* Wl[3] = {Wt1, Wt2, Wt3};
  const float*  Bl[3] = {b1, b2, b3};
  for (int l = 0; l < 3; ++l) {
    mfma_gemm_k<DIM, false><<<mgrid, 256, 0, stream>>>(h, Wl[l], nullptr, y, N_NODES);
    gather_k<DIM, true><<<(N_NODES * (DIM/8) + 255) / 256, 256, 0, stream>>>(
        y, row_ptr, csr_src, Bl[l], h);
  }

  // ---- pool + post-MLP ----
  pool_post_k<<<N_GRAPHS, 128, 0, stream>>>(h, batch, wp, bp, out);
}

// Round 11
// 306.922 us; speedup vs baseline: 1.0886x; 1.0156x over previous
//
#include <hip/hip_runtime.h>
#include <hip/hip_fp16.h>
#include <hip/hip_cooperative_groups.h>

namespace cg = cooperative_groups;

// GIN forward, round 11: cooperative single-kernel (14 phases, grid.sync)
// with LDS cut to 36.9KB (W-only GEMM staging; A direct-from-global into
// registers) + occupancy-checked fallback to 13 per-phase launches.
// R10 failed because 69.6KB LDS left zero co-residency margin and the
// cooperative launch was rejected silently.

#define N_NODES  50000
#define N_EDGES  600000
#define N_FEAT   64
#define DIM      128
#define N_GRAPHS 1024
#define NB_SCAN  49        // ceil(50000/1024)
#define GRID     512
#define TPB      256
#define GT128    ((N_NODES + 127) / 128)   // 391 gemm tiles
#define SMEM_BYTES 36864                   // max(Ws 128*136*2, Os 128*144*2)

typedef _Float16 f16x8 __attribute__((ext_vector_type(8)));
typedef float    f32x4 __attribute__((ext_vector_type(4)));

#define CNTZ  (N_NODES / 4)
#define XWORK (N_NODES * N_FEAT / 4)
#define PREP_TOTAL (CNTZ + XWORK + N_FEAT * DIM + 3 * DIM * DIM)

struct Params {
  const float* x; const int* src; const int* dst; const int* batch;
  const float *w0, *b0, *w1, *b1, *w2, *b2, *w3, *b3, *wp, *bp;
  float* out;
  __half *xh, *y, *h, *Wt0, *Wt1, *Wt2, *Wt3;
  int *cnt, *fill, *part, *row_ptr, *csr_src;
};

// ---------------- phase bodies ----------------

__device__ __forceinline__ void prep_phase(const Params& p) {
  for (int i0 = blockIdx.x * TPB + threadIdx.x; i0 < PREP_TOTAL;
       i0 += gridDim.x * TPB) {
    int i = i0;
    if (i < CNTZ) {
      *reinterpret_cast<int4*>(p.cnt + i * 4) = make_int4(0, 0, 0, 0);
      continue;
    }
    i -= CNTZ;
    if (i < XWORK) {
      float4 v = *reinterpret_cast<const float4*>(p.x + (size_t)i * 4);
      union { __half2 h2[2]; uint2 u; } pk;
      pk.h2[0] = __floats2half2_rn(v.x, v.y);
      pk.h2[1] = __floats2half2_rn(v.z, v.w);
      *reinterpret_cast<uint2*>(p.xh + (size_t)i * 4) = pk.u;
      continue;
    }
    int j = i - XWORK;
    if (j < N_FEAT * DIM) {
      int k = j >> 7, n = j & 127;
      p.Wt0[n * N_FEAT + k] = __float2half(p.w0[j]);
      continue;
    }
    j -= N_FEAT * DIM;
    int wsel = j / (DIM * DIM);
    int jj = j - wsel * (DIM * DIM);
    int k = jj >> 7, n = jj & 127;
    const float* W = (wsel == 0) ? p.w1 : (wsel == 1) ? p.w2 : p.w3;
    __half* Wt     = (wsel == 0) ? p.Wt1 : (wsel == 1) ? p.Wt2 : p.Wt3;
    Wt[n * DIM + k] = __float2half(W[jj]);
  }
}

__device__ __forceinline__ void hist_phase(const Params& p) {
  for (int e = blockIdx.x * TPB + threadIdx.x; e < N_EDGES;
       e += gridDim.x * TPB)
    atomicAdd(&p.cnt[p.dst[e]], 1);
}

__device__ __forceinline__ void scan_part_phase(const Params& p, char* smem) {
  int b = blockIdx.x;
  if (b >= NB_SCAN) return;
  int* ws = reinterpret_cast<int*>(smem);
  int t = threadIdx.x;
  int base = b * 1024 + t * 4;
  int s = 0;
  if (base + 3 < N_NODES) {
    int4 v = *reinterpret_cast<const int4*>(p.cnt + base);
    s = v.x + v.y + v.z + v.w;
  } else {
    for (int i = 0; i < 4; ++i) if (base + i < N_NODES) s += p.cnt[base + i];
  }
  for (int off = 32; off; off >>= 1) s += __shfl_down(s, off, 64);
  int lane = t & 63, wv = t >> 6;
  if (lane == 0) ws[wv] = s;
  __syncthreads();
  if (t == 0) p.part[b] = ws[0] + ws[1] + ws[2] + ws[3];
}

__device__ __forceinline__ void scan_write_phase(const Params& p, char* smem) {
  int b = blockIdx.x;
  if (b >= NB_SCAN) return;
  int* wsum = reinterpret_cast<int*>(smem);
  int* blk_off_s = reinterpret_cast<int*>(smem) + 4;
  int t = threadIdx.x;
  int lane = t & 63, wv = t >> 6;
  int base = b * 1024 + t * 4;

  if (base + 3 < N_NODES)
    *reinterpret_cast<int4*>(p.fill + base) = make_int4(0, 0, 0, 0);
  else
    for (int i = 0; i < 4; ++i) if (base + i < N_NODES) p.fill[base + i] = 0;

  if (t < 64) {
    int v = (t < NB_SCAN) ? p.part[t] : 0;
    int incl = v;
    for (int off = 1; off < 64; off <<= 1) {
      int u = __shfl_up(incl, off, 64);
      if (t >= off) incl += u;
    }
    if (t == b) *blk_off_s = incl - v;
  }

  int v[4];
#pragma unroll
  for (int i = 0; i < 4; ++i) v[i] = (base + i < N_NODES) ? p.cnt[base + i] : 0;
  int ls = v[0] + v[1] + v[2] + v[3];
  int incl = ls;
  for (int off = 1; off < 64; off <<= 1) {
    int u = __shfl_up(incl, off, 64);
    if (lane >= off) incl += u;
  }
  if (lane == 63) wsum[wv] = incl;
  __syncthreads();
  int woff = 0;
  for (int w = 0; w < wv; ++w) woff += wsum[w];
  int off0 = *blk_off_s + woff + (incl - ls);
  int rp0 = off0, rp1 = off0 + v[0], rp2 = rp1 + v[1], rp3 = rp2 + v[2];
  if (base + 3 < N_NODES)
    *reinterpret_cast<int4*>(p.row_ptr + base) = make_int4(rp0, rp1, rp2, rp3);
  else {
    int rp[4] = {rp0, rp1, rp2, rp3};
    for (int i = 0; i < 4; ++i) if (base + i < N_NODES) p.row_ptr[base + i] = rp[i];
  }
  if (b == 0 && t == 0) p.row_ptr[N_NODES] = N_EDGES;
}

__device__ __forceinline__ void fill_phase(const Params& p) {
  for (int e = blockIdx.x * TPB + threadIdx.x; e < N_EDGES;
       e += gridDim.x * TPB) {
    int d = p.dst[e];
    int pos = p.row_ptr[d] + atomicAdd(&p.fill[d], 1);
    p.csr_src[pos] = p.src[e];
  }
}

// gather: F/8 lanes per node, f16x8 per lane, 4-deep unroll, grid-stride.
template<int F, bool BR>
__device__ __forceinline__ void gather_phase(
    const __half* yIn, const float* bias, __half* hout, const Params& p) {
  constexpr int CH = F / 8;
  const f16x8* yv = reinterpret_cast<const f16x8*>(yIn);
  for (int gid = blockIdx.x * TPB + threadIdx.x; gid < N_NODES * CH;
       gid += gridDim.x * TPB) {
    int node = gid / CH;
    int l    = gid % CH;
    int beg = p.row_ptr[node], end = p.row_ptr[node + 1];

    f16x8 self = yv[(size_t)node * CH + l];
    float acc[8];
#pragma unroll
    for (int v = 0; v < 8; ++v) acc[v] = (float)self[v];

    int e = beg;
    for (; e + 3 < end; e += 4) {
      int s0 = p.csr_src[e+0], s1 = p.csr_src[e+1];
      int s2 = p.csr_src[e+2], s3 = p.csr_src[e+3];
      f16x8 v0 = yv[(size_t)s0 * CH + l];
      f16x8 v1 = yv[(size_t)s1 * CH + l];
      f16x8 v2 = yv[(size_t)s2 * CH + l];
      f16x8 v3 = yv[(size_t)s3 * CH + l];
#pragma unroll
      for (int v = 0; v < 8; ++v)
        acc[v] += ((float)v0[v] + (float)v1[v]) + ((float)v2[v] + (float)v3[v]);
    }
    for (; e < end; ++e) {
      f16x8 v0 = yv[(size_t)p.csr_src[e] * CH + l];
#pragma unroll
      for (int v = 0; v < 8; ++v) acc[v] += (float)v0[v];
    }

    f16x8 o;
    if (BR) {
      float4 b0 = *reinterpret_cast<const float4*>(bias + l * 8);
      float4 b1 = *reinterpret_cast<const float4*>(bias + l * 8 + 4);
      float bb[8] = {b0.x, b0.y, b0.z, b0.w, b1.x, b1.y, b1.z, b1.w};
#pragma unroll
      for (int v = 0; v < 8; ++v) o[v] = (_Float16)fmaxf(acc[v] + bb[v], 0.f);
    } else {
#pragma unroll
      for (int v = 0; v < 8; ++v) o[v] = (_Float16)acc[v];
    }
    reinterpret_cast<f16x8*>(hout)[(size_t)node * CH + l] = o;
  }
}

// MFMA GEMM: 128-row tiles (grid-strided). W staged in LDS; A-fragments loaded
// direct global->VGPR (each tile row read exactly once; rows of 4 quads cover
// 64B contiguous per row per k-chunk). Epilogue repacks via LDS (aliases Ws).
template<int K, bool EPI>
__device__ __forceinline__ void gemm_phase(
    const __half* A, const __half* Wt, const float* bias, __half* yOut,
    char* smem) {
  constexpr int KP = K + 8;
  constexpr int OSP = 144;
  constexpr int NKC = K / 32;            // k-chunks (mfma K=32)
  __half (*Ws)[KP]  = reinterpret_cast<__half(*)[KP]>(smem);
  __half (*Os)[OSP] = reinterpret_cast<__half(*)[OSP]>(smem);

  int tid = threadIdx.x;
  int w = tid >> 6, lane = tid & 63;
  int quad = lane >> 4, m = lane & 15;

  for (int tile = blockIdx.x; tile < GT128; tile += gridDim.x) {
    int row0 = tile * 128;

    // stage W tile (reused by all 4 waves x 8 col-tiles)
    for (int i = tid; i < 128 * (K / 8); i += TPB) {
      int r = i / (K / 8), c = (i % (K / 8)) * 8;
      *reinterpret_cast<f16x8*>(&Ws[r][c]) =
          *reinterpret_cast<const f16x8*>(Wt + (size_t)r * K + c);
    }

    // prefetch A fragments for both 16-row subtiles, all k-chunks
    f16x8 areg[2][NKC];
#pragma unroll
    for (int s = 0; s < 2; ++s) {
      int row = row0 + w * 32 + s * 16 + m;
      row = min(row, N_NODES - 1);
      const f16x8* Ar = reinterpret_cast<const f16x8*>(A + (size_t)row * K);
#pragma unroll
      for (int kc = 0; kc < NKC; ++kc)
        areg[s][kc] = Ar[kc * 4 + quad];
    }
    __syncthreads();   // Ws ready

    f32x4 acc[2][8];
#pragma unroll
    for (int s = 0; s < 2; ++s)
#pragma unroll
      for (int t = 0; t < 8; ++t) acc[s][t] = (f32x4){0.f, 0.f, 0.f, 0.f};

#pragma unroll
    for (int kc = 0; kc < NKC; ++kc) {
#pragma unroll
      for (int t = 0; t < 8; ++t) {
        f16x8 b = *reinterpret_cast<const f16x8*>(&Ws[t * 16 + m][kc * 32 + quad * 8]);
        acc[0][t] = __builtin_amdgcn_mfma_f32_16x16x32_f16(areg[0][kc], b, acc[0][t], 0, 0, 0);
        acc[1][t] = __builtin_amdgcn_mfma_f32_16x16x32_f16(areg[1][kc], b, acc[1][t], 0, 0, 0);
      }
    }

    __syncthreads();   // Ws reads done; Os aliases

#pragma unroll
    for (int t = 0; t < 8; ++t) {
      float bv = EPI ? bias[t * 16 + m] : 0.f;
#pragma unroll
      for (int s = 0; s < 2; ++s)
#pragma unroll
        for (int r = 0; r < 4; ++r) {
          float v = acc[s][t][r];
          if (EPI) v = fmaxf(v + bv, 0.f);
          Os[w * 32 + s * 16 + quad * 4 + r][t * 16 + m] = __float2half(v);
        }
    }
    __syncthreads();

#pragma unroll
    for (int it = 0; it < 8; ++it) {
      int i = tid + it * TPB;
      int r = i >> 4, c = (i & 15) * 8;
      int row = row0 + r;
      if (row < N_NODES)
        *reinterpret_cast<f16x8*>(yOut + (size_t)row * 128 + c) =
            *reinterpret_cast<const f16x8*>(&Os[r][c]);
    }
    __syncthreads();   // Os consumed before next tile re-stages Ws
  }
}

__device__ __forceinline__ void pool_phase(const Params& p, char* smem) {
  float* xs = reinterpret_cast<float*>(smem);
  int col = threadIdx.x;
  for (int g = blockIdx.x; g < N_GRAPHS; g += gridDim.x) {
    int lo = 0, hi = N_NODES;
    while (lo < hi) { int mid = (lo + hi) >> 1; if (p.batch[mid] < g) lo = mid + 1; else hi = mid; }
    int beg = lo;
    hi = N_NODES;
    while (lo < hi) { int mid = (lo + hi) >> 1; if (p.batch[mid] < g + 1) lo = mid + 1; else hi = mid; }
    int end = lo;

    if (col < DIM) {
      float acc = 0.f;
      for (int n = beg; n < end; ++n) acc += __half2float(p.h[(size_t)n * DIM + col]);
      float cnt = fmaxf((float)(end - beg), 1.0f);
      xs[col] = acc / cnt;
    }
    __syncthreads();
    if (col < DIM) {
      float o = p.bp[col];
      for (int k = 0; k < DIM; ++k)
        o = fmaf(xs[k], p.wp[(size_t)k * DIM + col], o);
      p.out[(size_t)g * DIM + col] = fmaxf(o, 0.f);
    }
    __syncthreads();
  }
}

// ---------------- cooperative single kernel ----------------
__global__ __launch_bounds__(TPB, 2) void gin_all_k(Params p) {
  cg::grid_group grid = cg::this_grid();
  __shared__ __align__(16) char smem[SMEM_BYTES];

  prep_phase(p);                                          grid.sync();
  hist_phase(p);                                          grid.sync();
  scan_part_phase(p, smem);                               grid.sync();
  scan_write_phase(p, smem);                              grid.sync();
  fill_phase(p);                                          grid.sync();

  gather_phase<N_FEAT, false>(p.xh, nullptr, p.y, p);     grid.sync();
  gemm_phase<N_FEAT, true>(p.y, p.Wt0, p.b0, p.h, smem);  grid.sync();

  gemm_phase<DIM, false>(p.h, p.Wt1, nullptr, p.y, smem); grid.sync();
  gather_phase<DIM, true>(p.y, p.b1, p.h, p);             grid.sync();
  gemm_phase<DIM, false>(p.h, p.Wt2, nullptr, p.y, smem); grid.sync();
  gather_phase<DIM, true>(p.y, p.b2, p.h, p);             grid.sync();
  gemm_phase<DIM, false>(p.h, p.Wt3, nullptr, p.y, smem); grid.sync();
  gather_phase<DIM, true>(p.y, p.b3, p.h, p);             grid.sync();

  pool_phase(p, smem);
}

// ---------------- fallback per-phase wrappers ----------------
__global__ __launch_bounds__(TPB) void prep_w(Params p)       { prep_phase(p); }
__global__ __launch_bounds__(TPB) void hist_w(Params p)       { hist_phase(p); }
__global__ __launch_bounds__(TPB) void scan_part_w(Params p)  {
  __shared__ __align__(16) char smem[64]; scan_part_phase(p, smem); }
__global__ __launch_bounds__(TPB) void scan_write_w(Params p) {
  __shared__ __align__(16) char smem[64]; scan_write_phase(p, smem); }
__global__ __launch_bounds__(TPB) void fill_w(Params p)       { fill_phase(p); }
template<int F, bool BR>
__global__ __launch_bounds__(TPB) void gather_w(Params p, const __half* yIn,
                                                const float* bias, __half* hout) {
  gather_phase<F, BR>(yIn, bias, hout, p);
}
template<int K, bool EPI>
__global__ __launch_bounds__(TPB) void gemm_w(Params p, const __half* A,
                                              const __half* Wt,
                                              const float* bias, __half* yOut) {
  __shared__ __align__(16) char smem[SMEM_BYTES];
  gemm_phase<K, EPI>(A, Wt, bias, yOut, smem);
}
__global__ __launch_bounds__(TPB) void pool_w(Params p) {
  __shared__ __align__(16) char smem[DIM * sizeof(float)];
  pool_phase(p, smem);
}

static void run_fallback(const Params& p, hipStream_t stream) {
  prep_w<<<(PREP_TOTAL + TPB - 1) / TPB, TPB, 0, stream>>>(p);
  hist_w<<<(N_EDGES + TPB - 1) / TPB, TPB, 0, stream>>>(p);
  scan_part_w<<<NB_SCAN, TPB, 0, stream>>>(p);
  scan_write_w<<<NB_SCAN, TPB, 0, stream>>>(p);
  fill_w<<<(N_EDGES + TPB - 1) / TPB, TPB, 0, stream>>>(p);

  gather_w<N_FEAT, false><<<(N_NODES * 8 + TPB - 1) / TPB, TPB, 0, stream>>>(
      p, p.xh, nullptr, p.y);
  gemm_w<N_FEAT, true><<<GT128, TPB, 0, stream>>>(p, p.y, p.Wt0, p.b0, p.h);

  const __half* Wl[3] = {p.Wt1, p.Wt2, p.Wt3};
  const float*  Bl[3] = {p.b1, p.b2, p.b3};
  for (int l = 0; l < 3; ++l) {
    gemm_w<DIM, false><<<GT128, TPB, 0, stream>>>(p, p.h, Wl[l], nullptr, p.y);
    gather_w<DIM, true><<<(N_NODES * 16 + TPB - 1) / TPB, TPB, 0, stream>>>(
        p, p.y, Bl[l], p.h);
  }
  pool_w<<<N_GRAPHS, TPB, 0, stream>>>(p);
}

extern "C" void kernel_launch(void* const* d_in, const int* in_sizes, int n_in,
                              void* d_out, int out_size, void* d_ws, size_t ws_size,
                              hipStream_t stream) {
  Params p;
  p.x     = (const float*)d_in[0];
  const int* ei = (const int*)d_in[1];
  p.src   = ei;
  p.dst   = ei + N_EDGES;
  p.batch = (const int*)d_in[2];
  p.w0 = (const float*)d_in[3];  p.b0 = (const float*)d_in[4];
  p.w1 = (const float*)d_in[5];  p.b1 = (const float*)d_in[6];
  p.w2 = (const float*)d_in[7];  p.b2 = (const float*)d_in[8];
  p.w3 = (const float*)d_in[9];  p.b3 = (const float*)d_in[10];
  p.wp = (const float*)d_in[11]; p.bp = (const float*)d_in[12];
  p.out = (float*)d_out;

  p.xh  = (__half*)d_ws;
  p.y   = p.xh + (size_t)N_NODES * N_FEAT;
  p.h   = p.y  + (size_t)N_NODES * DIM;
  p.Wt0 = p.h  + (size_t)N_NODES * DIM;
  p.Wt1 = p.Wt0 + N_FEAT * DIM;
  p.Wt2 = p.Wt1 + DIM * DIM;
  p.Wt3 = p.Wt2 + DIM * DIM;
  p.cnt     = (int*)(p.Wt3 + DIM * DIM);
  p.fill    = p.cnt + N_NODES;
  p.part    = p.fill + N_NODES;
  p.row_ptr = p.part + 64;
  p.csr_src = p.row_ptr + (N_NODES + 1);

  // capture-safe, deterministic capability check
  int dev = 0;
  hipGetDevice(&dev);
  int coop = 0, ncu = 0, nb = 0;
  hipDeviceGetAttribute(&coop, hipDeviceAttributeCooperativeLaunch, dev);
  hipDeviceGetAttribute(&ncu, hipDeviceAttributeMultiprocessorCount, dev);
  hipOccupancyMaxActiveBlocksPerMultiprocessor(&nb, (const void*)gin_all_k,
                                               TPB, 0);
  bool use_coop = coop && ((long)nb * ncu >= GRID);

  if (use_coop) {
    void* args[] = {&p};
    hipError_t err = hipLaunchCooperativeKernel((void*)gin_all_k, dim3(GRID),
                                                dim3(TPB), args, 0, stream);
    if (err == hipSuccess) return;
  }
  run_fallback(p, stream);
}